// Round 12
// baseline (132.652 us; speedup 1.0000x reference)
//
#include <hip/hip_runtime.h>
#include <hip/hip_fp16.h>
#include <math.h>

#define BDIM 4
#define LDIM 512
#define EDIM 1024
#define HDIM 128
#define TILE 32            // interior y-tile per block; s-grid 33x33 (1 halo)
#define NT   16            // 16*32 = 512 exact; 16*16*4 = 1024 blocks, no tail
#define K2   2.885390081777927f   // 2/ln(2)

typedef unsigned short ushort_t;
typedef __attribute__((ext_vector_type(8))) _Float16 half8;
typedef __attribute__((ext_vector_type(4))) float f32x4;

struct __align__(16) H8 { __half2 p[4]; };
union HU { H8 h; half8 v; };

// ---------------------------------------------------------------------------
// Kernel 0: W1 (1024x128 f32, k-major) -> Wt (128x1024 f16, n-major, k-contig)
// ---------------------------------------------------------------------------
__global__ __launch_bounds__(256) void wcvt(const float* __restrict__ W1,
                                            ushort_t* __restrict__ Wt) {
  const int g = (int)blockIdx.x * 256 + threadIdx.x;  // 0..16383
  const int n = g & 127, k8 = g >> 7;                 // k8: 0..127
  float v[8];
#pragma unroll
  for (int j = 0; j < 8; ++j) v[j] = W1[(size_t)(k8 * 8 + j) * HDIM + n];
  H8 o;
#pragma unroll
  for (int j = 0; j < 4; ++j) o.p[j] = __floats2half2_rn(v[2 * j], v[2 * j + 1]);
  *(H8*)&Wt[(size_t)n * EDIM + k8 * 8] = o;
}

// ---------------------------------------------------------------------------
// Kernel 1 (unchanged from R11, -5us vs R10): hid = relu(emb@W1+b1), f16 out;
// rec rows scaled by -K2. No LDS/barriers; 4-deep register load pipeline.
// ---------------------------------------------------------------------------
__global__ __launch_bounds__(256) void gemm_direct(
    const float* __restrict__ rec, const float* __restrict__ lig,
    const ushort_t* __restrict__ Wt, const float* __restrict__ b1,
    ushort_t* __restrict__ hid) {
  const int gw = (int)blockIdx.x * 4 + (threadIdx.x >> 6);  // 0..2047
  const int l = threadIdx.x & 63;
  const int strip = gw >> 3;
  const int nidx = gw & 7;
  const int r0 = strip * 16;
  const int m = l & 15, q = l >> 4;
  const float* arow = ((r0 < BDIM * LDIM)
                           ? rec + (size_t)r0 * EDIM
                           : lig + (size_t)(r0 - BDIM * LDIM) * EDIM) +
                      (size_t)m * EDIM + q * 8;
  const ushort_t* brow = Wt + (size_t)(nidx * 16 + m) * EDIM + q * 8;

  f32x4 acc = {0.f, 0.f, 0.f, 0.f};
  for (int blk = 0; blk < 8; ++blk) {
    float4 alo[4], ahi[4];
    half8 bf[4];
#pragma unroll
    for (int j = 0; j < 4; ++j) {
      const int k0 = (blk * 4 + j) * 32;
      alo[j] = *(const float4*)(arow + k0);
      ahi[j] = *(const float4*)(arow + k0 + 4);
      bf[j] = *(const half8*)(brow + k0);
    }
#pragma unroll
    for (int j = 0; j < 4; ++j) {
      HU au;
      au.h.p[0] = __floats2half2_rn(alo[j].x, alo[j].y);
      au.h.p[1] = __floats2half2_rn(alo[j].z, alo[j].w);
      au.h.p[2] = __floats2half2_rn(ahi[j].x, ahi[j].y);
      au.h.p[3] = __floats2half2_rn(ahi[j].z, ahi[j].w);
      acc = __builtin_amdgcn_mfma_f32_16x16x32_f16(au.v, bf[j], acc, 0, 0, 0);
    }
  }
  const float scale = (r0 < BDIM * LDIM) ? -K2 : 1.0f;
  const int col = nidx * 16 + m;
  const float bias = b1[col];
#pragma unroll
  for (int r = 0; r < 4; ++r) {
    float v = fmaxf(acc[r] + bias, 0.f) * scale;
    ((_Float16*)hid)[(size_t)(r0 + q * 4 + r) * HDIM + col] = (_Float16)v;
  }
}

// ---------------------------------------------------------------------------
// Kernel 2: 32x32 y-tile (33x33 s-grid). G = u*P3(u), u = exp2(r'*l).
// MFMA path covers s(0..31, 0..31); edge strips (pi=32 / qj=32, 65 pairs)
// via f32 VALU by one wave. Rows padded to 130 halves (65 dwords, =1 mod 32)
// -> ll frag reads drop from 8-way to <=4-way conflicts. 1024 blocks exact.
// ---------------------------------------------------------------------------
__global__ __launch_bounds__(256, 4) void bilinear_max(
    const ushort_t* __restrict__ hid, const float* __restrict__ cw,
    const float* __restrict__ cb, float* __restrict__ partial) {
  __shared__ ushort_t rl[33][130];   // 130 halves = 65 dwords stride
  __shared__ ushort_t ll[33][130];
  __shared__ float4 sl[33][34];      // f32 taps per (pi,qj)
  __shared__ float wred[4];
  __shared__ float wpart[2][4];

  const int t = threadIdx.x;
  const int b = blockIdx.z;
  const int ib = (int)blockIdx.y * TILE - 1;
  const int jb = (int)blockIdx.x * TILE - 1;
  const int w = t >> 6, l = t & 63;
  const int q = l >> 4, c15 = l & 15;

  // wsum_k = sum_h w_k[h]
  if (t < HDIM) {
    float4 w4 = *(const float4*)&cw[t * 4];
#pragma unroll
    for (int off = 32; off > 0; off >>= 1) {
      w4.x += __shfl_down(w4.x, off, 64);
      w4.y += __shfl_down(w4.y, off, 64);
      w4.z += __shfl_down(w4.z, off, 64);
      w4.w += __shfl_down(w4.w, off, 64);
    }
    if ((t & 63) == 0) {
      wpart[t >> 6][0] = w4.x; wpart[t >> 6][1] = w4.y;
      wpart[t >> 6][2] = w4.z; wpart[t >> 6][3] = w4.w;
    }
  }

  // B-frag: -2*w_tap for tap = c15 (cols >= 4 zero), per 32-h chunk c.
  half8 wf[4];
#pragma unroll
  for (int c = 0; c < 4; ++c) {
#pragma unroll
    for (int j = 0; j < 8; ++j) {
      float v = (c15 < 4) ? cw[(size_t)(c * 32 + q * 8 + j) * 4 + c15] : 0.f;
      wf[c][j] = (_Float16)(-2.f * v);
    }
  }

  // stage 33+33 rows x 16 octets
  H8 z;
  z.p[0] = z.p[1] = z.p[2] = z.p[3] = __floats2half2_rn(0.f, 0.f);
  for (int p = t; p < 66 * 16; p += 256) {
    int r = p >> 4, seg = (p & 15) * 8;
    if (r < 33) {
      int i = ib + r;
      H8 v = z;
      if (i >= 0) v = *(const H8*)&hid[((size_t)(b * LDIM + i)) * HDIM + seg];
      *(H8*)&rl[r][seg] = v;
    } else {
      int j = jb + (r - 33);
      H8 v = z;
      if (j >= 0) v = *(const H8*)&hid[((size_t)((BDIM + b) * LDIM + j)) * HDIM + seg];
      *(H8*)&ll[r - 33][seg] = v;
    }
  }
  __syncthreads();
  const float wsum_v = (c15 < 4) ? (wpart[0][c15] + wpart[1][c15]) : 0.f;

  // phase B (MFMA): wave w covers pi in [8w, 8w+8); g -> (pi, qj half)
  const __half2 D0 = __float2half2_rn(0.998539f);
  const __half2 D1 = __float2half2_rn(-0.947090f);
  const __half2 D2 = __float2half2_rn(0.676154f);
  const __half2 D3 = __float2half2_rn(-0.228646f);
#define POLYG(U) \
  __hmul2(U, __hfma2(U, __hfma2(U, __hfma2(U, D3, D2), D1), D0))

  for (int g = 0; g < 16; ++g) {
    const int ii = w * 8 + (g >> 1);
    const int jj0 = (g & 1) << 4;
    f32x4 acc = {0.f, 0.f, 0.f, 0.f};
#pragma unroll
    for (int c = 0; c < 4; ++c) {
      HU ru, lu, gu;
      ru.v = *(const half8*)&rl[ii][c * 32 + q * 8];
      lu.v = *(const half8*)&ll[jj0 + c15][c * 32 + q * 8];
      __half2 u0 = h2exp2(__hmul2(ru.h.p[0], lu.h.p[0]));
      __half2 u1 = h2exp2(__hmul2(ru.h.p[1], lu.h.p[1]));
      __half2 u2 = h2exp2(__hmul2(ru.h.p[2], lu.h.p[2]));
      __half2 u3 = h2exp2(__hmul2(ru.h.p[3], lu.h.p[3]));
      gu.h.p[0] = POLYG(u0);
      gu.h.p[1] = POLYG(u1);
      gu.h.p[2] = POLYG(u2);
      gu.h.p[3] = POLYG(u3);
      acc = __builtin_amdgcn_mfma_f32_16x16x32_f16(gu.v, wf[c], acc, 0, 0, 0);
    }
    if (c15 < 4) {
#pragma unroll
      for (int r = 0; r < 4; ++r)
        ((float*)&sl[ii][jj0 + q * 4 + r])[c15] = wsum_v + acc[r];
    }
  }
#undef POLYG

  // phase B (edge, f32 VALU): 65 pairs: (pi=e, 32) for e<33; (32, e-33) else.
  if (t < 65) {
    const int pi = (t < 33) ? t : 32;
    const int qj = (t < 33) ? 32 : (t - 33);
    const float ws0 = wpart[0][0] + wpart[1][0];
    const float ws1 = wpart[0][1] + wpart[1][1];
    const float ws2 = wpart[0][2] + wpart[1][2];
    const float ws3 = wpart[0][3] + wpart[1][3];
    float4 sa = make_float4(0.f, 0.f, 0.f, 0.f);
    for (int h = 0; h < HDIM; ++h) {
      float rv = (float)(*(const _Float16*)&rl[pi][h]);
      float lv = (float)(*(const _Float16*)&ll[qj][h]);
      float u = __builtin_amdgcn_exp2f(rv * lv);
      float gg = u * fmaf(u, fmaf(u, fmaf(u, -0.228646f, 0.676154f), -0.947090f), 0.998539f);
      float4 w4 = *(const float4*)&cw[h * 4];
      sa.x = fmaf(-2.f * gg, w4.x, sa.x);
      sa.y = fmaf(-2.f * gg, w4.y, sa.y);
      sa.z = fmaf(-2.f * gg, w4.z, sa.z);
      sa.w = fmaf(-2.f * gg, w4.w, sa.w);
    }
    sl[pi][qj] = make_float4(ws0 + sa.x, ws1 + sa.y, ws2 + sa.z, ws3 + sa.w);
  }
  __syncthreads();

  // phase C: y[i,j] = cb + s00(iy-1,jj-1)+s01(iy-1,jj)+s10(iy,jj-1)+s11(iy,jj)
  // iy,jj in 1..32 -> all 32x32 points valid (exact tiling, no guards).
  float m = -INFINITY;
  const float cbv = cb[0];
  for (int p = t; p < 1024; p += 256) {
    int jj = (p & 31) + 1, iy = (p >> 5) + 1;
    float v = cbv + sl[iy - 1][jj - 1].x + sl[iy - 1][jj].y
                  + sl[iy][jj - 1].z + sl[iy][jj].w;
    m = fmaxf(m, v);
  }
#pragma unroll
  for (int off = 32; off > 0; off >>= 1) m = fmaxf(m, __shfl_down(m, off, 64));
  if ((t & 63) == 0) wred[t >> 6] = m;
  __syncthreads();
  if (t == 0) {
    float mm = fmaxf(fmaxf(wred[0], wred[1]), fmaxf(wred[2], wred[3]));
    partial[((size_t)b * NT + blockIdx.y) * NT + blockIdx.x] = mm;
  }
}

// ---------------------------------------------------------------------------
// Kernel 3: reduce 16x16 partials per batch, sigmoid, write 4 outputs.
// ---------------------------------------------------------------------------
__global__ __launch_bounds__(64) void finalize(const float* __restrict__ partial,
                                               float* __restrict__ out) {
  const int b = blockIdx.x, t = threadIdx.x;
  float m = -INFINITY;
  for (int p = t; p < NT * NT; p += 64) m = fmaxf(m, partial[b * NT * NT + p]);
#pragma unroll
  for (int off = 32; off > 0; off >>= 1) m = fmaxf(m, __shfl_down(m, off, 64));
  if (t == 0) out[b] = 1.f / (1.f + expf(-m));
}

extern "C" void kernel_launch(void* const* d_in, const int* in_sizes, int n_in,
                              void* d_out, int out_size, void* d_ws, size_t ws_size,
                              hipStream_t stream) {
  const float* rec = (const float*)d_in[0];
  const float* lig = (const float*)d_in[1];
  const float* W1  = (const float*)d_in[2];
  const float* b1  = (const float*)d_in[3];
  const float* cw  = (const float*)d_in[4];   // (1,H,2,2): {w00,w01,w10,w11} per h
  const float* cb  = (const float*)d_in[5];
  float* out = (float*)d_out;

  ushort_t* Wt   = (ushort_t*)d_ws;                       // 128x1024 f16 = 256 KB
  ushort_t* hid  = Wt + (size_t)HDIM * EDIM;              // 4096x128 f16 = 1 MB
  float* partial = (float*)(hid + (size_t)2 * BDIM * LDIM * HDIM);  // 1024 f32

  wcvt<<<dim3(64), 256, 0, stream>>>(W1, Wt);
  gemm_direct<<<dim3(512), 256, 0, stream>>>(rec, lig, Wt, b1, hid);
  bilinear_max<<<dim3(NT, NT, BDIM), 256, 0, stream>>>(hid, cw, cb, partial);
  finalize<<<dim3(BDIM), 64, 0, stream>>>(partial, out);
}

// Round 13
// 130.743 us; speedup vs baseline: 1.0146x; 1.0146x over previous
//
#include <hip/hip_runtime.h>
#include <hip/hip_fp16.h>
#include <math.h>

#define BDIM 4
#define LDIM 512
#define EDIM 1024
#define HDIM 128
#define TILE 32            // y-tile per block; s-grid 33x33 (1 halo)
#define NT   16            // 16*32 = 512 exact; 1024 blocks, no tail
#define K2   2.885390081777927f   // 2/ln(2)

typedef unsigned short ushort_t;
typedef __attribute__((ext_vector_type(8))) _Float16 half8;
typedef __attribute__((ext_vector_type(4))) float f32x4;

struct __align__(16) H8 { __half2 p[4]; };
union HU { H8 h; half8 v; };

// ---------------------------------------------------------------------------
// Kernel 1: hid = relu(emb @ W1 + b1), f16 out; rec rows scaled by -K2 so the
// bilinear exp2 arg is r*l (u in (0,1]). W1 read directly (f32, k-major,
// coalesced 64B per 16-lane group, L2-hot) and converted in-flight — no wcvt.
// No LDS/barriers; 4-deep register load pipeline.
// ---------------------------------------------------------------------------
__global__ __launch_bounds__(256) void gemm_direct(
    const float* __restrict__ rec, const float* __restrict__ lig,
    const float* __restrict__ W1, const float* __restrict__ b1,
    ushort_t* __restrict__ hid) {
  const int gw = (int)blockIdx.x * 4 + (threadIdx.x >> 6);  // 0..2047
  const int l = threadIdx.x & 63;
  const int strip = gw >> 3;
  const int nidx = gw & 7;
  const int r0 = strip * 16;
  const int m = l & 15, q = l >> 4;
  const float* arow = ((r0 < BDIM * LDIM)
                           ? rec + (size_t)r0 * EDIM
                           : lig + (size_t)(r0 - BDIM * LDIM) * EDIM) +
                      (size_t)m * EDIM + q * 8;
  const int col = nidx * 16 + m;
  const float* wcol = W1 + col;          // stride HDIM per k

  f32x4 acc = {0.f, 0.f, 0.f, 0.f};
  for (int blk = 0; blk < 8; ++blk) {
    float4 alo[4], ahi[4];
    float bw[4][8];
#pragma unroll
    for (int j = 0; j < 4; ++j) {
      const int k0 = (blk * 4 + j) * 32 + q * 8;
      alo[j] = *(const float4*)(arow + (blk * 4 + j) * 32);
      ahi[j] = *(const float4*)(arow + (blk * 4 + j) * 32 + 4);
#pragma unroll
      for (int kk = 0; kk < 8; ++kk)
        bw[j][kk] = wcol[(size_t)(k0 + kk) * HDIM];
    }
#pragma unroll
    for (int j = 0; j < 4; ++j) {
      HU au, bu;
      au.h.p[0] = __floats2half2_rn(alo[j].x, alo[j].y);
      au.h.p[1] = __floats2half2_rn(alo[j].z, alo[j].w);
      au.h.p[2] = __floats2half2_rn(ahi[j].x, ahi[j].y);
      au.h.p[3] = __floats2half2_rn(ahi[j].z, ahi[j].w);
      bu.h.p[0] = __floats2half2_rn(bw[j][0], bw[j][1]);
      bu.h.p[1] = __floats2half2_rn(bw[j][2], bw[j][3]);
      bu.h.p[2] = __floats2half2_rn(bw[j][4], bw[j][5]);
      bu.h.p[3] = __floats2half2_rn(bw[j][6], bw[j][7]);
      acc = __builtin_amdgcn_mfma_f32_16x16x32_f16(au.v, bu.v, acc, 0, 0, 0);
    }
  }
  const float scale = (r0 < BDIM * LDIM) ? -K2 : 1.0f;
  const float bias = b1[col];
#pragma unroll
  for (int r = 0; r < 4; ++r) {
    float v = fmaxf(acc[r] + bias, 0.f) * scale;
    ((_Float16*)hid)[(size_t)(r0 + q * 4 + r) * HDIM + col] = (_Float16)v;
  }
}

// ---------------------------------------------------------------------------
// Kernel 2: 32x32 y-tile (33x33 s-grid). G = u*P3(u), u = exp2(r'*l).
// lu frags hoisted to registers (invariant across the 8 ii of a jj-half):
// LDS b128 reads/wave 128 -> 72, kills the 16-row strided conflict pattern.
// Taps stored f16 (4 x u16 per cell) -> 26.2 KB LDS -> 5+ blocks/CU.
// Edge strips (pi=32 / qj=32) by one wave in f32. 1024 blocks exact.
// ---------------------------------------------------------------------------
__global__ __launch_bounds__(256, 5) void bilinear_max(
    const ushort_t* __restrict__ hid, const float* __restrict__ cw,
    const float* __restrict__ cb, float* __restrict__ partial) {
  __shared__ ushort_t rl[33][130];   // 65-dword row stride
  __shared__ ushort_t ll[33][130];
  __shared__ ushort_t sl4[33][34][4];  // f16 taps {s00,s01,s10,s11}
  __shared__ float wred[4];
  __shared__ float wpart[2][4];

  const int t = threadIdx.x;
  const int b = blockIdx.z;
  const int ib = (int)blockIdx.y * TILE - 1;
  const int jb = (int)blockIdx.x * TILE - 1;
  const int w = t >> 6, l = t & 63;
  const int q = l >> 4, c15 = l & 15;

  // wsum_k = sum_h w_k[h]
  if (t < HDIM) {
    float4 w4 = *(const float4*)&cw[t * 4];
#pragma unroll
    for (int off = 32; off > 0; off >>= 1) {
      w4.x += __shfl_down(w4.x, off, 64);
      w4.y += __shfl_down(w4.y, off, 64);
      w4.z += __shfl_down(w4.z, off, 64);
      w4.w += __shfl_down(w4.w, off, 64);
    }
    if ((t & 63) == 0) {
      wpart[t >> 6][0] = w4.x; wpart[t >> 6][1] = w4.y;
      wpart[t >> 6][2] = w4.z; wpart[t >> 6][3] = w4.w;
    }
  }

  // B-frag: -2*w_tap for tap = c15 (cols >= 4 zero), per 32-h chunk c.
  half8 wf[4];
#pragma unroll
  for (int c = 0; c < 4; ++c) {
#pragma unroll
    for (int j = 0; j < 8; ++j) {
      float v = (c15 < 4) ? cw[(size_t)(c * 32 + q * 8 + j) * 4 + c15] : 0.f;
      wf[c][j] = (_Float16)(-2.f * v);
    }
  }

  // stage 33+33 rows x 16 octets
  H8 z;
  z.p[0] = z.p[1] = z.p[2] = z.p[3] = __floats2half2_rn(0.f, 0.f);
  for (int p = t; p < 66 * 16; p += 256) {
    int r = p >> 4, seg = (p & 15) * 8;
    if (r < 33) {
      int i = ib + r;
      H8 v = z;
      if (i >= 0) v = *(const H8*)&hid[((size_t)(b * LDIM + i)) * HDIM + seg];
      *(H8*)&rl[r][seg] = v;
    } else {
      int j = jb + (r - 33);
      H8 v = z;
      if (j >= 0) v = *(const H8*)&hid[((size_t)((BDIM + b) * LDIM + j)) * HDIM + seg];
      *(H8*)&ll[r - 33][seg] = v;
    }
  }
  __syncthreads();
  const float wsum_v = (c15 < 4) ? (wpart[0][c15] + wpart[1][c15]) : 0.f;

  // phase B (MFMA): for each jj-half, hoist lu to regs; loop 8 ii rows.
  const __half2 D0 = __float2half2_rn(0.998539f);
  const __half2 D1 = __float2half2_rn(-0.947090f);
  const __half2 D2 = __float2half2_rn(0.676154f);
  const __half2 D3 = __float2half2_rn(-0.228646f);
#define POLYG(U) \
  __hmul2(U, __hfma2(U, __hfma2(U, __hfma2(U, D3, D2), D1), D0))

#pragma unroll
  for (int hf = 0; hf < 2; ++hf) {
    const int jj0 = hf << 4;
    HU lu[4];
#pragma unroll
    for (int c = 0; c < 4; ++c)
      lu[c].v = *(const half8*)&ll[jj0 + c15][c * 32 + q * 8];
    for (int ii8 = 0; ii8 < 8; ++ii8) {
      const int ii = w * 8 + ii8;
      f32x4 acc = {0.f, 0.f, 0.f, 0.f};
#pragma unroll
      for (int c = 0; c < 4; ++c) {
        HU ru, gu;
        ru.v = *(const half8*)&rl[ii][c * 32 + q * 8];
        __half2 u0 = h2exp2(__hmul2(ru.h.p[0], lu[c].h.p[0]));
        __half2 u1 = h2exp2(__hmul2(ru.h.p[1], lu[c].h.p[1]));
        __half2 u2 = h2exp2(__hmul2(ru.h.p[2], lu[c].h.p[2]));
        __half2 u3 = h2exp2(__hmul2(ru.h.p[3], lu[c].h.p[3]));
        gu.h.p[0] = POLYG(u0);
        gu.h.p[1] = POLYG(u1);
        gu.h.p[2] = POLYG(u2);
        gu.h.p[3] = POLYG(u3);
        acc = __builtin_amdgcn_mfma_f32_16x16x32_f16(gu.v, wf[c], acc, 0, 0, 0);
      }
      // D: col = lane&15 = tap, row = q*4+reg = jj offset within half
      if (c15 < 4) {
#pragma unroll
        for (int r = 0; r < 4; ++r) {
          _Float16 hv = (_Float16)(wsum_v + acc[r]);
          sl4[ii][jj0 + q * 4 + r][c15] = *(ushort_t*)&hv;
        }
      }
    }
  }
#undef POLYG

  // phase B (edge, f32): 65 pairs: (pi=e,32) e<33; (32, e-33) else.
  if (t < 65) {
    const int pi = (t < 33) ? t : 32;
    const int qj = (t < 33) ? 32 : (t - 33);
    float4 sa = make_float4(0.f, 0.f, 0.f, 0.f);
    for (int h = 0; h < HDIM; ++h) {
      float rv = (float)(*(const _Float16*)&rl[pi][h]);
      float lv = (float)(*(const _Float16*)&ll[qj][h]);
      float u = __builtin_amdgcn_exp2f(rv * lv);
      float gg = u * fmaf(u, fmaf(u, fmaf(u, -0.228646f, 0.676154f), -0.947090f), 0.998539f);
      float4 w4 = *(const float4*)&cw[h * 4];
      sa.x = fmaf(-2.f * gg, w4.x, sa.x);
      sa.y = fmaf(-2.f * gg, w4.y, sa.y);
      sa.z = fmaf(-2.f * gg, w4.z, sa.z);
      sa.w = fmaf(-2.f * gg, w4.w, sa.w);
    }
#pragma unroll
    for (int k = 0; k < 4; ++k) {
      _Float16 hv = (_Float16)(wpart[0][k] + wpart[1][k] + ((float*)&sa)[k]);
      sl4[pi][qj][k] = *(ushort_t*)&hv;
    }
  }
  __syncthreads();

  // phase C: y = cb + s00(iy-1,jj-1)+s01(iy-1,jj)+s10(iy,jj-1)+s11(iy,jj)
  float m = -INFINITY;
  const float cbv = cb[0];
  for (int p = t; p < 1024; p += 256) {
    int jj = (p & 31) + 1, iy = (p >> 5) + 1;
    float v = cbv + (float)(*(const _Float16*)&sl4[iy - 1][jj - 1][0])
                  + (float)(*(const _Float16*)&sl4[iy - 1][jj][1])
                  + (float)(*(const _Float16*)&sl4[iy][jj - 1][2])
                  + (float)(*(const _Float16*)&sl4[iy][jj][3]);
    m = fmaxf(m, v);
  }
#pragma unroll
  for (int off = 32; off > 0; off >>= 1) m = fmaxf(m, __shfl_down(m, off, 64));
  if ((t & 63) == 0) wred[t >> 6] = m;
  __syncthreads();
  if (t == 0) {
    float mm = fmaxf(fmaxf(wred[0], wred[1]), fmaxf(wred[2], wred[3]));
    partial[((size_t)b * NT + blockIdx.y) * NT + blockIdx.x] = mm;
  }
}

// ---------------------------------------------------------------------------
// Kernel 3: reduce 16x16 partials per batch, sigmoid, write 4 outputs.
// ---------------------------------------------------------------------------
__global__ __launch_bounds__(64) void finalize(const float* __restrict__ partial,
                                               float* __restrict__ out) {
  const int b = blockIdx.x, t = threadIdx.x;
  float m = -INFINITY;
  for (int p = t; p < NT * NT; p += 64) m = fmaxf(m, partial[b * NT * NT + p]);
#pragma unroll
  for (int off = 32; off > 0; off >>= 1) m = fmaxf(m, __shfl_down(m, off, 64));
  if (t == 0) out[b] = 1.f / (1.f + expf(-m));
}

extern "C" void kernel_launch(void* const* d_in, const int* in_sizes, int n_in,
                              void* d_out, int out_size, void* d_ws, size_t ws_size,
                              hipStream_t stream) {
  const float* rec = (const float*)d_in[0];
  const float* lig = (const float*)d_in[1];
  const float* W1  = (const float*)d_in[2];
  const float* b1  = (const float*)d_in[3];
  const float* cw  = (const float*)d_in[4];   // (1,H,2,2): {w00,w01,w10,w11} per h
  const float* cb  = (const float*)d_in[5];
  float* out = (float*)d_out;

  ushort_t* hid  = (ushort_t*)d_ws;                        // 4096x128 f16 = 1 MB
  float* partial = (float*)(hid + (size_t)2 * BDIM * LDIM * HDIM);  // 1024 f32

  gemm_direct<<<dim3(512), 256, 0, stream>>>(rec, lig, W1, b1, hid);
  bilinear_max<<<dim3(NT, NT, BDIM), 256, 0, stream>>>(hid, cw, cb, partial);
  finalize<<<dim3(BDIM), 64, 0, stream>>>(partial, out);
}